// Round 11
// baseline (1102.867 us; speedup 1.0000x reference)
//
#include <hip/hip_runtime.h>
#include <math.h>

#define BB  16
#define TT  1024
#define NN  128
#define WIN 30
#define NWD 498          // number of windows
#define DM  256          // D_MODEL
#define IND 384          // 3*N
#define GW  9            // windows per staging group in k24
#define NB  512          // mega-kernel grid (2 blocks/CU at 67KB LDS -> all co-resident)

#define INV_W (1.0f/498.0f)

#define SARR (BB*NN*NN)  // one b-major NxN array

// workspace offsets in floats
#define OFF_A     0                        // rstd/sqrt(29) per (b,w,ch)
#define OFF_G     (OFF_A    + BB*NWD*NN)   // sqrt(30)*mu*a per (b,w,ch)
#define OFF_CM2   (OFF_G    + BB*NWD*NN)
#define OFF_CM4   (OFF_CM2  + SARR)
#define OFF_CM8   (OFF_CM4  + SARR)
#define OFF_AD    (OFF_CM8  + SARR)        // 3 per-d rowcorr arrays, (b*3+d) major
#define OFF_PART  (OFF_AD   + 3*SARR)      // 768 blocks x 16384 floats
// PART is fully consumed by mega stage A before these are written -> alias:
#define OFF_ANORM OFF_PART
#define OFF_BUFA  (OFF_ANORM + SARR)
#define OFF_BUFB  (OFF_BUFA + BB*NN*DM)
#define OFF_SYNC  (OFF_PART + 768*16384)   // 2 uints, past end of PART

// ---------------------------------------------------------------- K1: sliding per-window channel stats
__global__ __launch_bounds__(128) void k1_stats(const float* __restrict__ x, float* __restrict__ ws) {
    int bx = blockIdx.x;
    int c = bx & 15, b = bx >> 4;
    int w0 = c*32, w1 = min(NWD, w0+32);
    int n = threadIdx.x;
    const float* xp = x + (size_t)b*TT*NN + n;

    float sum = 0.f, sq = 0.f;
    for (int t = 2*w0; t < 2*w0 + WIN; ++t) {
        float v = xp[(size_t)t*NN];
        sum += v; sq = fmaf(v, v, sq);
    }
    for (int w = w0; w < w1; ++w) {
        if (w > w0) {
            float o0 = xp[(size_t)(2*w-2)*NN], o1 = xp[(size_t)(2*w-1)*NN];
            float n0 = xp[(size_t)(2*w+28)*NN], n1 = xp[(size_t)(2*w+29)*NN];
            sum += (n0 + n1) - (o0 + o1);
            sq  += (n0*n0 + n1*n1) - (o0*o0 + o1*o1);
        }
        float mean = sum * (1.0f/30.0f);
        float ss = sq - 30.0f*mean*mean;
        float var = fmaxf(ss * (1.0f/29.0f), 1e-8f);
        float a = (1.0f / sqrtf(var)) * 0.185695338f;   // fold 1/sqrt(29)
        ws[OFF_A + ((size_t)b*NWD + w)*NN + n] = a;
        ws[OFF_G + ((size_t)b*NWD + w)*NN + n] = mean * a * 5.477225575f;   // sqrt(30)*mu*a
    }
}

// ---------------------------------------------------------------- K24: incremental sliding cross-products (r8 structure)
__global__ __launch_bounds__(256) __attribute__((amdgpu_waves_per_eu(3, 3)))
void k24_inc(const float* __restrict__ x, float* __restrict__ ws) {
    __shared__ __align__(16) float xr[64][NN];   // circular x-row buffer, slot = t & 63 (32 KB)
    __shared__ __align__(16) float sa[GW][NN];
    __shared__ __align__(16) float sg[GW][NN];
    int bx = blockIdx.x;
    int wc = bx & 7;
    int slab = (bx >> 3) % 6;
    int b = bx / 48;
    const char IS[6] = {0,0,0,0,1,1};
    const char JS[6] = {0,1,2,3,2,3};
    int is = IS[slab], js = JS[slab];
    int w0 = wc * 63, w1 = min(NWD, w0 + 63);
    int tid = threadIdx.x;
    int jg = tid & 7, ig = tid >> 3;
    int i0 = is*64 + ig*2;
    int j0 = js*32 + jg*4;

    const float* xb = x + (size_t)b*TT*NN;
    const float* Ab = ws + OFF_A + (size_t)b*NWD*NN;
    const float* Gb = ws + OFF_G + (size_t)b*NWD*NN;

    float P[2][4];
    float S1[2][4], S2[2][4], S3[2][4], S4[2][4], S5[2][4], S6[2][4], S7[2][4], S8[2][4];
#pragma unroll
    for (int p=0;p<2;++p)
#pragma unroll
        for (int q=0;q<4;++q) {
            P[p][q]=0.f;
            S1[p][q]=0.f;S2[p][q]=0.f;S3[p][q]=0.f;S4[p][q]=0.f;
            S5[p][q]=0.f;S6[p][q]=0.f;S7[p][q]=0.f;S8[p][q]=0.f;
        }

    auto moments = [&](int k) {
        float2 ai = *(const float2*)&sa[k][i0];
        float2 gi = *(const float2*)&sg[k][i0];
        float4 aj = *(const float4*)&sa[k][j0];
        float4 gj = *(const float4*)&sg[k][j0];
        float av[2] = {ai.x, ai.y};
        float mg[2] = {-gi.x, -gi.y};
        float aw[4] = {aj.x, aj.y, aj.z, aj.w};
        float gw[4] = {gj.x, gj.y, gj.z, gj.w};
#pragma unroll
        for (int p=0;p<2;++p)
#pragma unroll
            for (int q=0;q<4;++q) {
                float aa  = av[p]*aw[q];
                float ngg = mg[p]*gw[q];
                float c   = fmaf(P[p][q], aa, ngg);
                float c2 = c*c;
                float c3 = c2*c;
                float c4 = c2*c2;
                S1[p][q] += c;
                S2[p][q] += c2;
                S3[p][q] += c3;
                S4[p][q] += c4;
                S5[p][q] = fmaf(c4, c,  S5[p][q]);
                S6[p][q] = fmaf(c3, c3, S6[p][q]);
                S7[p][q] = fmaf(c3, c4, S7[p][q]);
                S8[p][q] = fmaf(c4, c4, S8[p][q]);
            }
    };

    int rlo = 2*w0;
    for (int wg = w0; wg < w1; wg += GW) {
        int m = min(GW, w1 - wg);
        __syncthreads();
        int rhi = 2*(wg + m - 1) + 29;
        int nr = rhi - rlo + 1;
        for (int idx = tid; idx < nr*32; idx += 256) {
            int r = idx >> 5, c4 = idx & 31;
            int t = rlo + r;
            *(float4*)&xr[t & 63][c4*4] = ((const float4*)(xb + (size_t)t*NN))[c4];
        }
        for (int idx = tid; idx < m*32; idx += 256) {
            int k = idx >> 5, c4 = idx & 31;
            *(float4*)&sa[k][c4*4] = ((const float4*)(Ab + (size_t)(wg+k)*NN))[c4];
        }
        for (int idx = tid; idx < m*32; idx += 256) {
            int k = idx >> 5, c4 = idx & 31;
            *(float4*)&sg[k][c4*4] = ((const float4*)(Gb + (size_t)(wg+k)*NN))[c4];
        }
        rlo = rhi + 1;
        __syncthreads();

        int kstart = 0;
        if (wg == w0) {
#pragma unroll 6
            for (int k = 0; k < WIN; ++k) {
                int t = 2*w0 + k;
                float2 xi = *(const float2*)&xr[t & 63][i0];
                float4 xj = *(const float4*)&xr[t & 63][j0];
                float av[2] = {xi.x, xi.y};
                float bv[4] = {xj.x, xj.y, xj.z, xj.w};
#pragma unroll
                for (int p=0;p<2;++p)
#pragma unroll
                    for (int q=0;q<4;++q) P[p][q] = fmaf(av[p], bv[q], P[p][q]);
            }
            moments(0);
            kstart = 1;
        }
        for (int k = kstart; k < m; ++k) {
            int w = wg + k;
            int tr[4] = {2*w - 2, 2*w - 1, 2*w + 28, 2*w + 29};
#pragma unroll
            for (int kk = 0; kk < 4; ++kk) {
                int t = tr[kk];
                float sgn = (kk < 2) ? -1.0f : 1.0f;
                float2 xi = *(const float2*)&xr[t & 63][i0];
                float4 xj = *(const float4*)&xr[t & 63][j0];
                float av[2] = {sgn*xi.x, sgn*xi.y};
                float bv[4] = {xj.x, xj.y, xj.z, xj.w};
#pragma unroll
                for (int p=0;p<2;++p)
#pragma unroll
                    for (int q=0;q<4;++q) P[p][q] = fmaf(av[p], bv[q], P[p][q]);
            }
            moments(k);
        }
    }

    float* tp = ws + OFF_PART + (size_t)bx*16384 + tid*8;
#define STORE_ARR(A, S) \
    *(float4*)&tp[(A)*2048]     = make_float4(S[0][0], S[0][1], S[0][2], S[0][3]); \
    *(float4*)&tp[(A)*2048 + 4] = make_float4(S[1][0], S[1][1], S[1][2], S[1][3]);
    STORE_ARR(0, S1) STORE_ARR(1, S2) STORE_ARR(2, S3) STORE_ARR(3, S4)
    STORE_ARR(4, S5) STORE_ARR(5, S6) STORE_ARR(6, S7) STORE_ARR(7, S8)
#undef STORE_ARR
}

// ---------------------------------------------------------------- device-scope grid barrier (all NB blocks co-resident)
__device__ __forceinline__ void grid_barrier(unsigned* ctr, unsigned* gen) {
    __syncthreads();
    if (threadIdx.x == 0) {
        unsigned g = __hip_atomic_load(gen, __ATOMIC_ACQUIRE, __HIP_MEMORY_SCOPE_AGENT);
        unsigned a = __hip_atomic_fetch_add(ctr, 1u, __ATOMIC_ACQ_REL, __HIP_MEMORY_SCOPE_AGENT);
        if (a == (unsigned)NB - 1u) {
            __hip_atomic_store(ctr, 0u, __ATOMIC_RELAXED, __HIP_MEMORY_SCOPE_AGENT);
            __hip_atomic_fetch_add(gen, 1u, __ATOMIC_ACQ_REL, __HIP_MEMORY_SCOPE_AGENT);
        } else {
            while (__hip_atomic_load(gen, __ATOMIC_ACQUIRE, __HIP_MEMORY_SCOPE_AGENT) == g)
                __builtin_amdgcn_s_sleep(8);
        }
    }
    __syncthreads();
}

// ---------------------------------------------------------------- KMEGA: kred -> {k5 | k78} -> k6 -> k98 -> k9 -> k12
__global__ __launch_bounds__(256) void kmega(const float* __restrict__ gamma, const float* __restrict__ beta,
                                             const float* __restrict__ W1, const float* __restrict__ b1,
                                             const float* __restrict__ W2, const float* __restrict__ b2,
                                             const float* __restrict__ Wc, const float* __restrict__ bc,
                                             float* __restrict__ ws, float* __restrict__ outp) {
    __shared__ __align__(16) float smem[NN*(NN+1) + 2*NN];   // 67KB (k5 stage is the max)
    unsigned* ctr = (unsigned*)(ws + OFF_SYNC);
    unsigned* gen = ctr + 1;
    int blk = blockIdx.x, tid = threadIdx.x;
    const char IS[6] = {0,0,0,0,1,1};
    const char JS[6] = {0,1,2,3,2,3};

    // ======== Stage A: reduce PART -> centered moments CM2/4/8 ========
    for (int idx = blk*256 + tid; idx < 96*2048; idx += NB*256) {
        int slab_id = idx >> 11, off = idx & 2047;
        int b = slab_id / 6, slab = slab_id % 6;
        int is = IS[slab], js = JS[slab];
        const float* base = ws + OFF_PART + (size_t)(b*48 + slab*8)*16384;
        float E[8];
#pragma unroll
        for (int a=0;a<8;++a) E[a] = 0.f;
        for (int c = 0; c < 8; ++c) {
            const float* tp = base + (size_t)c*16384;
#pragma unroll
            for (int a=0;a<8;++a) E[a] += tp[a*2048 + off];
        }
        int tid_old = off >> 3, e = off & 7;
        int ig = tid_old >> 3, jg = tid_old & 7;
        int p = e >> 2, q = e & 3;
        int i = is*64 + ig*2 + p;
        int j = js*32 + jg*4 + q;
        float cm2, cm4, cm8;
        if (i == j) { cm2 = 0.f; cm4 = 0.f; cm8 = 0.f; }
        else {
            float e1 = E[0]*INV_W, e2 = E[1]*INV_W, e3 = E[2]*INV_W, e4 = E[3]*INV_W;
            float e5 = E[4]*INV_W, e6 = E[5]*INV_W, e7 = E[6]*INV_W, e8 = E[7]*INV_W;
            float m  = e1;
            float m2 = m*m, m3 = m2*m, m4 = m2*m2, m5 = m4*m, m6 = m3*m3, m8 = m4*m4;
            cm2 = e2 - m2;
            cm4 = e4 - 4.f*m*e3 + 6.f*m2*e2 - 3.f*m4;
            cm8 = e8 - 8.f*m*e7 + 28.f*m2*e6 - 56.f*m3*e5 + 70.f*m4*e4
                     - 56.f*m5*e3 + 28.f*m6*e2 - 7.f*m8;
        }
        float* C2 = ws + OFF_CM2 + (size_t)b*NN*NN;
        float* C4 = ws + OFF_CM4 + (size_t)b*NN*NN;
        float* C8 = ws + OFF_CM8 + (size_t)b*NN*NN;
        C2[i*NN + j] = cm2; C2[j*NN + i] = cm2;
        C4[i*NN + j] = cm4; C4[j*NN + i] = cm4;
        C8[i*NN + j] = cm8; C8[j*NN + i] = cm8;
    }
    grid_barrier(ctr, gen);

    // ======== Stage B: k5 rowwise_corr (blocks 0..383) | k78 LN+gemm1 (blocks 384..511) ========
    if (blk < 384) {
        int jq = blk & 3, di = (blk >> 2) % 3, b = blk / 12;
        float* Xc = smem;                       // [128][129]
        float* rmn = smem + NN*(NN+1);
        float* iden = rmn + NN;
        const float* cm = ws + (di==0 ? OFF_CM2 : (di==1 ? OFF_CM4 : OFF_CM8)) + (size_t)b*NN*NN;
        for (int idx = tid; idx < NN*NN; idx += 256) {
            int n = idx >> 7, f = idx & 127;
            Xc[n*(NN+1)+f] = cm[idx];
        }
        __syncthreads();
        if (tid < NN) {
            float s = 0.f;
            for (int f = 0; f < NN; ++f) s += Xc[tid*(NN+1)+f];
            rmn[tid] = s * (1.0f/NN);
        }
        __syncthreads();
        for (int idx = tid; idx < NN*NN; idx += 256) {
            int n = idx >> 7, f = idx & 127;
            Xc[n*(NN+1)+f] -= rmn[n];
        }
        __syncthreads();
        if (tid < NN) {
            float s = 0.f;
            for (int f = 0; f < NN; ++f) { float v = Xc[tid*(NN+1)+f]; s = fmaf(v, v, s); }
            iden[tid] = 1.0f/sqrtf(fmaxf(s, 1e-8f));
        }
        __syncthreads();
        int n0 = (tid >> 4)*8, m0 = jq*32 + (tid & 15)*2;
        float acc[8][2];
#pragma unroll
        for (int k=0;k<8;++k) { acc[k][0]=0.f; acc[k][1]=0.f; }
        for (int f = 0; f < NN; ++f) {
            float am0 = Xc[(m0  )*(NN+1)+f];
            float am1 = Xc[(m0+1)*(NN+1)+f];
#pragma unroll
            for (int k=0;k<8;++k) {
                float an = Xc[(n0+k)*(NN+1)+f];
                acc[k][0] = fmaf(an, am0, acc[k][0]);
                acc[k][1] = fmaf(an, am1, acc[k][1]);
            }
        }
        float* Ad = ws + OFF_AD + (size_t)(b*3 + di)*NN*NN;
#pragma unroll
        for (int k=0;k<8;++k)
#pragma unroll
            for (int l=0;l<2;++l) {
                int gi = n0+k, gj = m0+l;
                float v = acc[k][l]*iden[gi]*iden[gj];
                if (gi == gj) v = 1.0f;
                Ad[gi*NN + gj] = v;
            }
    } else {
        int r0 = (blk - 384) * 16;              // 16 rows of (b*NN+n) space
        float* Xs = smem;                       // [16][IND]
        float* sm = smem + 16*IND;
        float* sr = sm + 16;
        for (int r = 0; r < 16; ++r) {
            int row = r0 + r;
            int b = row >> 7, n = row & 127;
            const float* c2 = ws + OFF_CM2 + ((size_t)b*NN + n)*NN;
            const float* c4 = ws + OFF_CM4 + ((size_t)b*NN + n)*NN;
            const float* c8 = ws + OFF_CM8 + ((size_t)b*NN + n)*NN;
            for (int c = tid; c < IND; c += 256)
                Xs[r*IND+c] = (c < 128) ? c2[c] : (c < 256) ? c4[c-128] : c8[c-256];
        }
        __syncthreads();
        {
            int team = tid >> 4, lane = tid & 15;
            float s = 0.f;
            for (int c = lane; c < IND; c += 16) s += Xs[team*IND + c];
#pragma unroll
            for (int o = 8; o > 0; o >>= 1) s += __shfl_down(s, o, 16);
            float mean = __shfl(s, 0, 16) * (1.0f/IND);
            float v = 0.f;
            for (int c = lane; c < IND; c += 16) { float d = Xs[team*IND + c] - mean; v = fmaf(d, d, v); }
#pragma unroll
            for (int o = 8; o > 0; o >>= 1) v += __shfl_down(v, o, 16);
            if (lane == 0) {
                sm[team] = mean;
                sr[team] = 1.0f / sqrtf(v*(1.0f/IND) + 1e-5f);
            }
        }
        __syncthreads();
        for (int r = 0; r < 16; ++r) {
            float mean = sm[r], rstd = sr[r];
            for (int c = tid; c < IND; c += 256)
                Xs[r*IND+c] = (Xs[r*IND+c] - mean)*rstd*gamma[c] + beta[c];
        }
        __syncthreads();
        float acc[16];
        float bv = b1[tid];
#pragma unroll
        for (int r = 0; r < 16; ++r) acc[r] = bv;
#pragma unroll 4
        for (int k = 0; k < IND; ++k) {
            float wv = W1[(size_t)k*DM + tid];
#pragma unroll
            for (int r = 0; r < 16; ++r) acc[r] = fmaf(Xs[r*IND+k], wv, acc[r]);
        }
        float* O = ws + OFF_BUFA;
#pragma unroll
        for (int r = 0; r < 16; ++r) O[(size_t)(r0+r)*DM + tid] = acc[r];
    }
    grid_barrier(ctr, gen);

    // ======== Stage C: adjacency normalize (blocks 0..15) ========
    if (blk < BB) {
        int b = blk;
        float* As = smem;                       // [128][129]
        float* dis = smem + NN*(NN+1);
        const float* A0 = ws + OFF_AD + (size_t)(b*3 + 0)*NN*NN;
        const float* A1 = ws + OFF_AD + (size_t)(b*3 + 1)*NN*NN;
        const float* A2 = ws + OFF_AD + (size_t)(b*3 + 2)*NN*NN;
        for (int idx = tid; idx < NN*NN; idx += 256) {
            int n = idx >> 7, m = idx & 127;
            int ji = m*NN + n;
            float s = A0[idx] + A0[ji] + A1[idx] + A1[ji] + A2[idx] + A2[ji];
            As[n*(NN+1)+m] = s * (1.0f/6.0f);
        }
        __syncthreads();
        if (tid < NN) {
            float d = 1.0f;
            for (int m = 0; m < NN; ++m) d += As[tid*(NN+1)+m];
            dis[tid] = sqrtf(1.0f / fmaxf(d, 1e-8f));
        }
        __syncthreads();
        float* An = ws + OFF_ANORM + (size_t)b*NN*NN;
        for (int idx = tid; idx < NN*NN; idx += 256) {
            int n = idx >> 7, m = idx & 127;
            float v = As[n*(NN+1)+m] + (n==m ? 1.0f : 0.0f);
            An[idx] = v * dis[n] * dis[m];
        }
    }
    grid_barrier(ctr, gen);

    // ======== Stage D: H = relu(An@M1); M2 = H@W2+b2  (512 blocks x 4 rows) ========
    {
        int b = blk >> 5, n0 = (blk & 31)*4;
        float* Ar = smem;                       // [4][128]
        float* Hs = smem + 4*NN;                // [4][256]
        const float* A = ws + OFF_ANORM + (size_t)b*NN*NN;
        if (tid < NN) {
#pragma unroll
            for (int r = 0; r < 4; ++r) Ar[r*NN + tid] = A[(n0+r)*NN + tid];
        }
        __syncthreads();
        float acc[4] = {0,0,0,0};
        const float* Z = ws + OFF_BUFA + (size_t)b*NN*DM;
#pragma unroll 4
        for (int m = 0; m < NN; ++m) {
            float z = Z[(size_t)m*DM + tid];
#pragma unroll
            for (int r = 0; r < 4; ++r) acc[r] = fmaf(Ar[r*NN + m], z, acc[r]);
        }
#pragma unroll
        for (int r = 0; r < 4; ++r) Hs[r*DM + tid] = fmaxf(acc[r], 0.0f);
        __syncthreads();
        float acc2[4];
        float bv = b2[tid];
#pragma unroll
        for (int r = 0; r < 4; ++r) acc2[r] = bv;
#pragma unroll 4
        for (int k = 0; k < DM; ++k) {
            float wv = W2[(size_t)k*DM + tid];
#pragma unroll
            for (int r = 0; r < 4; ++r) acc2[r] = fmaf(Hs[r*DM + k], wv, acc2[r]);
        }
        float* O = ws + OFF_BUFB + (size_t)b*NN*DM;
#pragma unroll
        for (int r = 0; r < 4; ++r) O[(size_t)(n0+r)*DM + tid] = acc2[r];
    }
    grid_barrier(ctr, gen);

    // ======== Stage E: H2 = relu(An@M2)  (512 blocks x 4 rows) ========
    {
        int b = blk >> 5, n0 = (blk & 31)*4;
        float* Ar = smem;
        const float* A = ws + OFF_ANORM + (size_t)b*NN*NN;
        if (tid < NN) {
#pragma unroll
            for (int r = 0; r < 4; ++r) Ar[r*NN + tid] = A[(n0+r)*NN + tid];
        }
        __syncthreads();
        float acc[4] = {0,0,0,0};
        const float* Z = ws + OFF_BUFB + (size_t)b*NN*DM;
#pragma unroll 4
        for (int m = 0; m < NN; ++m) {
            float z = Z[(size_t)m*DM + tid];
#pragma unroll
            for (int r = 0; r < 4; ++r) acc[r] = fmaf(Ar[r*NN + m], z, acc[r]);
        }
        float* O = ws + OFF_BUFA + (size_t)b*NN*DM;
#pragma unroll
        for (int r = 0; r < 4; ++r) O[(size_t)(n0+r)*DM + tid] = fmaxf(acc[r], 0.0f);
    }
    grid_barrier(ctr, gen);

    // ======== Stage F: mean-pool + sigmoid head (blocks 0..15) ========
    if (blk < BB) {
        int b = blk;
        float* red = smem;
        const float* H = ws + OFF_BUFA + (size_t)b*NN*DM;
        float s = 0.f;
        for (int n = 0; n < NN; ++n) s += H[(size_t)n*DM + tid];
        red[tid] = s * (1.0f/NN) * Wc[tid];
        __syncthreads();
        for (int o = 128; o > 0; o >>= 1) { if (tid < o) red[tid] += red[tid+o]; __syncthreads(); }
        if (tid == 0) outp[b] = 1.0f/(1.0f + expf(-(red[0] + bc[0])));
    }
}

// ----------------------------------------------------------------
extern "C" void kernel_launch(void* const* d_in, const int* in_sizes, int n_in,
                              void* d_out, int out_size, void* d_ws, size_t ws_size,
                              hipStream_t stream) {
    (void)in_sizes; (void)n_in; (void)out_size; (void)ws_size;
    const float* x     = (const float*)d_in[0];
    const float* gamma = (const float*)d_in[1];
    const float* beta  = (const float*)d_in[2];
    const float* W1    = (const float*)d_in[3];
    const float* b1    = (const float*)d_in[4];
    const float* W2    = (const float*)d_in[5];
    const float* b2    = (const float*)d_in[6];
    const float* Wc    = (const float*)d_in[7];
    const float* bc    = (const float*)d_in[8];
    float* ws  = (float*)d_ws;
    float* out = (float*)d_out;

    // zero the grid-barrier counter+generation (ws is re-poisoned before every launch)
    hipMemsetAsync(ws + OFF_SYNC, 0, 2*sizeof(unsigned), stream);

    k1_stats <<<BB*16,  128, 0, stream>>>(x, ws);
    k24_inc  <<<BB*6*8, 256, 0, stream>>>(x, ws);
    kmega    <<<NB,     256, 0, stream>>>(gamma, beta, W1, b1, W2, b2, Wc, bc, ws, out);
}

// Round 12
// 264.055 us; speedup vs baseline: 4.1767x; 4.1767x over previous
//
#include <hip/hip_runtime.h>
#include <math.h>

#define BB  16
#define TT  1024
#define NN  128
#define WIN 30
#define NWD 498          // number of windows
#define DM  256          // D_MODEL
#define IND 384          // 3*N
#define GW  9            // windows per staging group in k24

#define INV_W (1.0f/498.0f)

#define SARR (BB*NN*NN)  // one b-major NxN array

// workspace offsets in floats
#define OFF_A     0                        // rstd/sqrt(29) per (b,w,ch)
#define OFF_G     (OFF_A    + BB*NWD*NN)   // sqrt(30)*mu*a per (b,w,ch)
#define OFF_CM2   (OFF_G    + BB*NWD*NN)
#define OFF_CM4   (OFF_CM2  + SARR)
#define OFF_CM8   (OFF_CM4  + SARR)
#define OFF_AD    (OFF_CM8  + SARR)        // 3 per-d rowcorr arrays, (b*3+d) major
#define OFF_PART  (OFF_AD   + 3*SARR)      // 768 blocks x 16384 floats
// PART is fully consumed by kred before these are written -> alias:
#define OFF_ANORM OFF_PART
#define OFF_BUFA  (OFF_ANORM + SARR)
#define OFF_BUFB  (OFF_BUFA + BB*NN*DM)

// ---------------------------------------------------------------- K1: sliding per-window channel stats
__global__ __launch_bounds__(128) void k1_stats(const float* __restrict__ x, float* __restrict__ ws) {
    int bx = blockIdx.x;
    int c = bx & 15, b = bx >> 4;
    int w0 = c*32, w1 = min(NWD, w0+32);
    int n = threadIdx.x;
    const float* xp = x + (size_t)b*TT*NN + n;

    float sum = 0.f, sq = 0.f;
    for (int t = 2*w0; t < 2*w0 + WIN; ++t) {
        float v = xp[(size_t)t*NN];
        sum += v; sq = fmaf(v, v, sq);
    }
    for (int w = w0; w < w1; ++w) {
        if (w > w0) {
            float o0 = xp[(size_t)(2*w-2)*NN], o1 = xp[(size_t)(2*w-1)*NN];
            float n0 = xp[(size_t)(2*w+28)*NN], n1 = xp[(size_t)(2*w+29)*NN];
            sum += (n0 + n1) - (o0 + o1);
            sq  += (n0*n0 + n1*n1) - (o0*o0 + o1*o1);
        }
        float mean = sum * (1.0f/30.0f);
        float ss = sq - 30.0f*mean*mean;
        float var = fmaxf(ss * (1.0f/29.0f), 1e-8f);
        float a = (1.0f / sqrtf(var)) * 0.185695338f;   // fold 1/sqrt(29)
        ws[OFF_A + ((size_t)b*NWD + w)*NN + n] = a;
        ws[OFF_G + ((size_t)b*NWD + w)*NN + n] = mean * a * 5.477225575f;   // sqrt(30)*mu*a
    }
}

// ---------------------------------------------------------------- K24: incremental sliding cross-products (r8 structure)
__global__ __launch_bounds__(256) __attribute__((amdgpu_waves_per_eu(3, 3)))
void k24_inc(const float* __restrict__ x, float* __restrict__ ws) {
    __shared__ __align__(16) float xr[64][NN];   // circular x-row buffer, slot = t & 63 (32 KB)
    __shared__ __align__(16) float sa[GW][NN];
    __shared__ __align__(16) float sg[GW][NN];
    int bx = blockIdx.x;
    int wc = bx & 7;
    int slab = (bx >> 3) % 6;
    int b = bx / 48;
    const char IS[6] = {0,0,0,0,1,1};
    const char JS[6] = {0,1,2,3,2,3};
    int is = IS[slab], js = JS[slab];
    int w0 = wc * 63, w1 = min(NWD, w0 + 63);
    int tid = threadIdx.x;
    int jg = tid & 7, ig = tid >> 3;
    int i0 = is*64 + ig*2;
    int j0 = js*32 + jg*4;

    const float* xb = x + (size_t)b*TT*NN;
    const float* Ab = ws + OFF_A + (size_t)b*NWD*NN;
    const float* Gb = ws + OFF_G + (size_t)b*NWD*NN;

    float P[2][4];
    float S1[2][4], S2[2][4], S3[2][4], S4[2][4], S5[2][4], S6[2][4], S7[2][4], S8[2][4];
#pragma unroll
    for (int p=0;p<2;++p)
#pragma unroll
        for (int q=0;q<4;++q) {
            P[p][q]=0.f;
            S1[p][q]=0.f;S2[p][q]=0.f;S3[p][q]=0.f;S4[p][q]=0.f;
            S5[p][q]=0.f;S6[p][q]=0.f;S7[p][q]=0.f;S8[p][q]=0.f;
        }

    auto moments = [&](int k) {
        float2 ai = *(const float2*)&sa[k][i0];
        float2 gi = *(const float2*)&sg[k][i0];
        float4 aj = *(const float4*)&sa[k][j0];
        float4 gj = *(const float4*)&sg[k][j0];
        float av[2] = {ai.x, ai.y};
        float mg[2] = {-gi.x, -gi.y};
        float aw[4] = {aj.x, aj.y, aj.z, aj.w};
        float gw[4] = {gj.x, gj.y, gj.z, gj.w};
#pragma unroll
        for (int p=0;p<2;++p)
#pragma unroll
            for (int q=0;q<4;++q) {
                float aa  = av[p]*aw[q];
                float ngg = mg[p]*gw[q];
                float c   = fmaf(P[p][q], aa, ngg);
                float c2 = c*c;
                float c3 = c2*c;
                float c4 = c2*c2;
                S1[p][q] += c;
                S2[p][q] += c2;
                S3[p][q] += c3;
                S4[p][q] += c4;
                S5[p][q] = fmaf(c4, c,  S5[p][q]);
                S6[p][q] = fmaf(c3, c3, S6[p][q]);
                S7[p][q] = fmaf(c3, c4, S7[p][q]);
                S8[p][q] = fmaf(c4, c4, S8[p][q]);
            }
    };

    int rlo = 2*w0;
    for (int wg = w0; wg < w1; wg += GW) {
        int m = min(GW, w1 - wg);
        __syncthreads();
        int rhi = 2*(wg + m - 1) + 29;
        int nr = rhi - rlo + 1;
        for (int idx = tid; idx < nr*32; idx += 256) {
            int r = idx >> 5, c4 = idx & 31;
            int t = rlo + r;
            *(float4*)&xr[t & 63][c4*4] = ((const float4*)(xb + (size_t)t*NN))[c4];
        }
        for (int idx = tid; idx < m*32; idx += 256) {
            int k = idx >> 5, c4 = idx & 31;
            *(float4*)&sa[k][c4*4] = ((const float4*)(Ab + (size_t)(wg+k)*NN))[c4];
        }
        for (int idx = tid; idx < m*32; idx += 256) {
            int k = idx >> 5, c4 = idx & 31;
            *(float4*)&sg[k][c4*4] = ((const float4*)(Gb + (size_t)(wg+k)*NN))[c4];
        }
        rlo = rhi + 1;
        __syncthreads();

        int kstart = 0;
        if (wg == w0) {
#pragma unroll 6
            for (int k = 0; k < WIN; ++k) {
                int t = 2*w0 + k;
                float2 xi = *(const float2*)&xr[t & 63][i0];
                float4 xj = *(const float4*)&xr[t & 63][j0];
                float av[2] = {xi.x, xi.y};
                float bv[4] = {xj.x, xj.y, xj.z, xj.w};
#pragma unroll
                for (int p=0;p<2;++p)
#pragma unroll
                    for (int q=0;q<4;++q) P[p][q] = fmaf(av[p], bv[q], P[p][q]);
            }
            moments(0);
            kstart = 1;
        }
        for (int k = kstart; k < m; ++k) {
            int w = wg + k;
            int tr[4] = {2*w - 2, 2*w - 1, 2*w + 28, 2*w + 29};
#pragma unroll
            for (int kk = 0; kk < 4; ++kk) {
                int t = tr[kk];
                float sgn = (kk < 2) ? -1.0f : 1.0f;
                float2 xi = *(const float2*)&xr[t & 63][i0];
                float4 xj = *(const float4*)&xr[t & 63][j0];
                float av[2] = {sgn*xi.x, sgn*xi.y};
                float bv[4] = {xj.x, xj.y, xj.z, xj.w};
#pragma unroll
                for (int p=0;p<2;++p)
#pragma unroll
                    for (int q=0;q<4;++q) P[p][q] = fmaf(av[p], bv[q], P[p][q]);
            }
            moments(k);
        }
    }

    float* tp = ws + OFF_PART + (size_t)bx*16384 + tid*8;
#define STORE_ARR(A, S) \
    *(float4*)&tp[(A)*2048]     = make_float4(S[0][0], S[0][1], S[0][2], S[0][3]); \
    *(float4*)&tp[(A)*2048 + 4] = make_float4(S[1][0], S[1][1], S[1][2], S[1][3]);
    STORE_ARR(0, S1) STORE_ARR(1, S2) STORE_ARR(2, S3) STORE_ARR(3, S4)
    STORE_ARR(4, S5) STORE_ARR(5, S6) STORE_ARR(6, S7) STORE_ARR(7, S8)
#undef STORE_ARR
}

// ---------------------------------------------------------------- Kred: reduce 8 chunk-partials -> centered moments
__global__ __launch_bounds__(256) void kred(float* __restrict__ ws) {
    int pair = blockIdx.x >> 3, sub = blockIdx.x & 7;
    int b = pair / 6, slab = pair % 6;
    const char IS[6] = {0,0,0,0,1,1};
    const char JS[6] = {0,1,2,3,2,3};
    int is = IS[slab], js = JS[slab];
    int off = sub*256 + threadIdx.x;          // 0..2047 within slab
    const float* base = ws + OFF_PART + (size_t)(b*48 + slab*8)*16384;

    float E[8];
#pragma unroll
    for (int a=0;a<8;++a) E[a] = 0.f;
    for (int c = 0; c < 8; ++c) {
        const float* tp = base + (size_t)c*16384;
#pragma unroll
        for (int a=0;a<8;++a) E[a] += tp[a*2048 + off];
    }

    int tid_old = off >> 3, e = off & 7;
    int ig = tid_old >> 3, jg = tid_old & 7;
    int p = e >> 2, q = e & 3;
    int i = is*64 + ig*2 + p;
    int j = js*32 + jg*4 + q;

    float cm2, cm4, cm8;
    if (i == j) {
        cm2 = 0.f; cm4 = 0.f; cm8 = 0.f;
    } else {
        float e1 = E[0]*INV_W, e2 = E[1]*INV_W, e3 = E[2]*INV_W, e4 = E[3]*INV_W;
        float e5 = E[4]*INV_W, e6 = E[5]*INV_W, e7 = E[6]*INV_W, e8 = E[7]*INV_W;
        float m  = e1;
        float m2 = m*m, m3 = m2*m, m4 = m2*m2, m5 = m4*m, m6 = m3*m3, m8 = m4*m4;
        cm2 = e2 - m2;
        cm4 = e4 - 4.f*m*e3 + 6.f*m2*e2 - 3.f*m4;
        cm8 = e8 - 8.f*m*e7 + 28.f*m2*e6 - 56.f*m3*e5 + 70.f*m4*e4
                 - 56.f*m5*e3 + 28.f*m6*e2 - 7.f*m8;
    }
    float* C2 = ws + OFF_CM2 + (size_t)b*NN*NN;
    float* C4 = ws + OFF_CM4 + (size_t)b*NN*NN;
    float* C8 = ws + OFF_CM8 + (size_t)b*NN*NN;
    C2[i*NN + j] = cm2; C2[j*NN + i] = cm2;
    C4[i*NN + j] = cm4; C4[j*NN + i] = cm4;
    C8[i*NN + j] = cm8; C8[j*NN + i] = cm8;
}

// ---------------------------------------------------------------- KB: merged k5 rowwise_corr (blocks 0..191) | k78 LN+gemm1 (192..447)
// Both depend only on CM (written by kred); outputs disjoint (AD vs BUFA).
__global__ __launch_bounds__(256) void kB(const float* __restrict__ gamma, const float* __restrict__ beta,
                                          const float* __restrict__ W1, const float* __restrict__ b1,
                                          float* __restrict__ ws) {
    __shared__ __align__(16) float smem[NN*(NN+1) + 2*NN];   // k5 view: Xc[128][129] + rmn + iden (~66.5 KB)
    int blk = blockIdx.x, tid = threadIdx.x;
    if (blk < 192) {
        // ---- k5: (b, di, j-quarter); 8x2 tiles over 128 x 32
        int rem = blk % 12;
        int b = blk / 12, di = rem >> 2, jq = rem & 3;
        float* Xc  = smem;                  // stride NN+1
        float* rmn = smem + NN*(NN+1);
        float* iden = rmn + NN;
        const float* cm = ws + (di==0 ? OFF_CM2 : (di==1 ? OFF_CM4 : OFF_CM8)) + (size_t)b*NN*NN;
        for (int idx = tid; idx < NN*NN; idx += 256) {
            int n = idx >> 7, f = idx & 127;
            Xc[n*(NN+1)+f] = cm[idx];
        }
        __syncthreads();
        if (tid < NN) {
            float s = 0.f;
            for (int f = 0; f < NN; ++f) s += Xc[tid*(NN+1)+f];
            rmn[tid] = s * (1.0f/NN);
        }
        __syncthreads();
        for (int idx = tid; idx < NN*NN; idx += 256) {
            int n = idx >> 7, f = idx & 127;
            Xc[n*(NN+1)+f] -= rmn[n];
        }
        __syncthreads();
        if (tid < NN) {
            float s = 0.f;
            for (int f = 0; f < NN; ++f) { float v = Xc[tid*(NN+1)+f]; s = fmaf(v, v, s); }
            iden[tid] = 1.0f/sqrtf(fmaxf(s, 1e-8f));
        }
        __syncthreads();
        int n0 = (tid >> 4)*8, m0 = jq*32 + (tid & 15)*2;
        float acc[8][2];
#pragma unroll
        for (int k=0;k<8;++k) { acc[k][0]=0.f; acc[k][1]=0.f; }
        for (int f = 0; f < NN; ++f) {
            float am0 = Xc[(m0  )*(NN+1)+f];
            float am1 = Xc[(m0+1)*(NN+1)+f];
#pragma unroll
            for (int k=0;k<8;++k) {
                float an = Xc[(n0+k)*(NN+1)+f];
                acc[k][0] = fmaf(an, am0, acc[k][0]);
                acc[k][1] = fmaf(an, am1, acc[k][1]);
            }
        }
        float* Ad = ws + OFF_AD + (size_t)(b*3 + di)*NN*NN;
#pragma unroll
        for (int k=0;k<8;++k)
#pragma unroll
            for (int l=0;l<2;++l) {
                int gi = n0+k, gj = m0+l;
                float v = acc[k][l]*iden[gi]*iden[gj];
                if (gi == gj) v = 1.0f;
                Ad[gi*NN + gj] = v;
            }
    } else {
        // ---- k78: LN + X@W1+b1 on 8 rows
        int r0 = (blk - 192) * 8;
        float* Xs = smem;                    // [8][IND]
        float* sm = smem + 8*IND;
        float* sr = sm + 8;
        for (int r = 0; r < 8; ++r) {
            int row = r0 + r;
            int b = row >> 7, n = row & 127;
            const float* c2 = ws + OFF_CM2 + ((size_t)b*NN + n)*NN;
            const float* c4 = ws + OFF_CM4 + ((size_t)b*NN + n)*NN;
            const float* c8 = ws + OFF_CM8 + ((size_t)b*NN + n)*NN;
            for (int c = tid; c < IND; c += 256)
                Xs[r*IND+c] = (c < 128) ? c2[c] : (c < 256) ? c4[c-128] : c8[c-256];
        }
        __syncthreads();
        {
            int team = tid >> 5, lane = tid & 31;
            float s = 0.f;
            for (int c = lane; c < IND; c += 32) s += Xs[team*IND + c];
#pragma unroll
            for (int o = 16; o > 0; o >>= 1) s += __shfl_down(s, o, 32);
            float mean = __shfl(s, 0, 32) * (1.0f/IND);
            float v = 0.f;
            for (int c = lane; c < IND; c += 32) { float d = Xs[team*IND + c] - mean; v = fmaf(d, d, v); }
#pragma unroll
            for (int o = 16; o > 0; o >>= 1) v += __shfl_down(v, o, 32);
            if (lane == 0) {
                sm[team] = mean;
                sr[team] = 1.0f / sqrtf(v*(1.0f/IND) + 1e-5f);
            }
        }
        __syncthreads();
        for (int r = 0; r < 8; ++r) {
            float mean = sm[r], rstd = sr[r];
            for (int c = tid; c < IND; c += 256)
                Xs[r*IND+c] = (Xs[r*IND+c] - mean)*rstd*gamma[c] + beta[c];
        }
        __syncthreads();
        float acc[8];
        float bv = b1[tid];
#pragma unroll
        for (int r = 0; r < 8; ++r) acc[r] = bv;
#pragma unroll 4
        for (int k = 0; k < IND; ++k) {
            float wv = W1[(size_t)k*DM + tid];
#pragma unroll
            for (int r = 0; r < 8; ++r) acc[r] = fmaf(Xs[r*IND+k], wv, acc[r]);
        }
        float* O = ws + OFF_BUFA;
#pragma unroll
        for (int r = 0; r < 8; ++r) O[(size_t)(r0+r)*DM + tid] = acc[r];
    }
}

// ---------------------------------------------------------------- K6: sum 3 d-arrays, symmetrize + normalize adjacency
__global__ __launch_bounds__(256) void k6_anorm(float* __restrict__ ws) {
    __shared__ float As[NN][NN+1];
    __shared__ float dis[NN];
    int b = blockIdx.x;
    const float* A0 = ws + OFF_AD + (size_t)(b*3 + 0)*NN*NN;
    const float* A1 = ws + OFF_AD + (size_t)(b*3 + 1)*NN*NN;
    const float* A2 = ws + OFF_AD + (size_t)(b*3 + 2)*NN*NN;
    int tid = threadIdx.x;
    for (int idx = tid; idx < NN*NN; idx += 256) {
        int n = idx >> 7, m = idx & 127;
        int ji = m*NN + n;
        float s = A0[idx] + A0[ji] + A1[idx] + A1[ji] + A2[idx] + A2[ji];
        As[n][m] = s * (1.0f/6.0f);
    }
    __syncthreads();
    if (tid < NN) {
        float d = 1.0f;
        for (int m = 0; m < NN; ++m) d += As[tid][m];
        dis[tid] = sqrtf(1.0f / fmaxf(d, 1e-8f));
    }
    __syncthreads();
    float* An = ws + OFF_ANORM + (size_t)b*NN*NN;
    for (int idx = tid; idx < NN*NN; idx += 256) {
        int n = idx >> 7, m = idx & 127;
        float v = As[n][m] + (n==m ? 1.0f : 0.0f);
        An[idx] = v * dis[n] * dis[m];
    }
}

// ---------------------------------------------------------------- K98: fused H=relu(An@M1); M2 = H@W2+b2
__global__ __launch_bounds__(256) void k98_propgemm(const float* __restrict__ W2, const float* __restrict__ b2,
                                                    float* __restrict__ ws) {
    __shared__ float Ar[8][NN];
    __shared__ float Hs[8][DM];
    int bx = blockIdx.x;
    int b = bx >> 4, n0 = (bx & 15)*8;
    int tid = threadIdx.x;
    const float* A = ws + OFF_ANORM + (size_t)b*NN*NN;
    if (tid < NN) {
#pragma unroll
        for (int r = 0; r < 8; ++r) Ar[r][tid] = A[(n0+r)*NN + tid];
    }
    __syncthreads();
    float acc[8] = {0,0,0,0,0,0,0,0};
    const float* Z = ws + OFF_BUFA + (size_t)b*NN*DM;
#pragma unroll 4
    for (int m = 0; m < NN; ++m) {
        float z = Z[(size_t)m*DM + tid];
#pragma unroll
        for (int r = 0; r < 8; ++r) acc[r] = fmaf(Ar[r][m], z, acc[r]);
    }
#pragma unroll
    for (int r = 0; r < 8; ++r) Hs[r][tid] = fmaxf(acc[r], 0.0f);
    __syncthreads();
    float acc2[8];
    float bv = b2[tid];
#pragma unroll
    for (int r = 0; r < 8; ++r) acc2[r] = bv;
#pragma unroll 4
    for (int k = 0; k < DM; ++k) {
        float wv = W2[(size_t)k*DM + tid];
#pragma unroll
        for (int r = 0; r < 8; ++r) acc2[r] = fmaf(Hs[r][k], wv, acc2[r]);
    }
    float* O = ws + OFF_BUFB + (size_t)b*NN*DM;
#pragma unroll
    for (int r = 0; r < 8; ++r) O[(size_t)(n0+r)*DM + tid] = acc2[r];
}

// ---------------------------------------------------------------- K9: H2 = relu(A_norm @ M2)
__global__ __launch_bounds__(256) void k9_prop(float* __restrict__ ws) {
    __shared__ float Ar[8][NN];
    int bx = blockIdx.x;
    int b = bx >> 4, n0 = (bx & 15)*8;
    int tid = threadIdx.x;
    const float* A = ws + OFF_ANORM + (size_t)b*NN*NN;
    if (tid < NN) {
#pragma unroll
        for (int r = 0; r < 8; ++r) Ar[r][tid] = A[(n0+r)*NN + tid];
    }
    __syncthreads();
    float acc[8] = {0,0,0,0,0,0,0,0};
    const float* Z = ws + OFF_BUFB + (size_t)b*NN*DM;
#pragma unroll 4
    for (int m = 0; m < NN; ++m) {
        float z = Z[(size_t)m*DM + tid];
#pragma unroll
        for (int r = 0; r < 8; ++r) acc[r] = fmaf(Ar[r][m], z, acc[r]);
    }
    float* O = ws + OFF_BUFA + (size_t)b*NN*DM;
#pragma unroll
    for (int r = 0; r < 8; ++r) O[(size_t)(n0+r)*DM + tid] = fmaxf(acc[r], 0.0f);
}

// ---------------------------------------------------------------- K12: mean-pool + sigmoid head
__global__ __launch_bounds__(256) void k12_head(const float* __restrict__ Wc, const float* __restrict__ bc,
                                                float* __restrict__ ws, float* __restrict__ outp) {
    __shared__ float red[256];
    int b = blockIdx.x, tid = threadIdx.x;
    const float* H = ws + OFF_BUFA + (size_t)b*NN*DM;
    float s = 0.f;
    for (int n = 0; n < NN; ++n) s += H[(size_t)n*DM + tid];
    red[tid] = s * (1.0f/NN) * Wc[tid];
    __syncthreads();
    for (int o = 128; o > 0; o >>= 1) { if (tid < o) red[tid] += red[tid+o]; __syncthreads(); }
    if (tid == 0) outp[b] = 1.0f/(1.0f + expf(-(red[0] + bc[0])));
}

// ----------------------------------------------------------------
extern "C" void kernel_launch(void* const* d_in, const int* in_sizes, int n_in,
                              void* d_out, int out_size, void* d_ws, size_t ws_size,
                              hipStream_t stream) {
    (void)in_sizes; (void)n_in; (void)out_size; (void)ws_size;
    const float* x     = (const float*)d_in[0];
    const float* gamma = (const float*)d_in[1];
    const float* beta  = (const float*)d_in[2];
    const float* W1    = (const float*)d_in[3];
    const float* b1    = (const float*)d_in[4];
    const float* W2    = (const float*)d_in[5];
    const float* b2    = (const float*)d_in[6];
    const float* Wc    = (const float*)d_in[7];
    const float* bc    = (const float*)d_in[8];
    float* ws  = (float*)d_ws;
    float* out = (float*)d_out;

    k1_stats   <<<BB*16,   128, 0, stream>>>(x, ws);
    k24_inc    <<<BB*6*8,  256, 0, stream>>>(x, ws);
    kred       <<<BB*6*8,  256, 0, stream>>>(ws);
    kB         <<<448,     256, 0, stream>>>(gamma, beta, W1, b1, ws);
    k6_anorm   <<<BB,      256, 0, stream>>>(ws);
    k98_propgemm<<<BB*16,  256, 0, stream>>>(W2, b2, ws);
    k9_prop    <<<BB*16,   256, 0, stream>>>(ws);
    k12_head   <<<BB,      256, 0, stream>>>(Wc, bc, ws, out);
}